// Round 14
// baseline (366.276 us; speedup 1.0000x reference)
//
#include <hip/hip_runtime.h>
#include <hip/hip_bf16.h>
#include <stdint.h>

#define BATCH 8
#define SEQ 2048
#define DMODEL 1024

typedef __attribute__((ext_vector_type(4))) float f32x4;
typedef __attribute__((ext_vector_type(16))) float f32x16;
typedef __attribute__((ext_vector_type(8))) short bf16x8;
typedef __attribute__((ext_vector_type(4))) uint32_t u32x4;
typedef __attribute__((ext_vector_type(2))) uint32_t u32x2;

#define MFMA32(a, b, c) __builtin_amdgcn_mfma_f32_32x32x16_bf16((a), (b), (c), 0, 0, 0)

// ---------------------------------------------------------------------------
// PK ("panel-k-major") operand layout for ALL bf16 GEMM operands:
//   elem(r,k) at offset (r>>4)*(Kd*16) + (k>>3)*128 + (r&15)*8 + (k&7)
//  * staging is contiguous + lane-linear in LDS (global_load_lds-legal);
//  * 32x32x16 fragment reads: lane l reads row l&31, k-slot (l>>5) of a
//    panel-pair -> four 16-lane groups each read a distinct contiguous 256B
//    chunk (uniform bank coverage, conflict-free).
// MFMA core: mfma_f32_32x32x16_bf16 (2382-2495 TF ceiling vs 2075 for 16x16).
// C/D map (HW-verified m74/m101): col=lane&31, row=(reg&3)+8*(reg>>2)+4*(lane>>5).
// ---------------------------------------------------------------------------

static __device__ __forceinline__ uint16_t f2bf(float f) {
    uint32_t u = __builtin_bit_cast(uint32_t, f);
    u += 0x7fffu + ((u >> 16) & 1u);   // round-to-nearest-even
    return (uint16_t)(u >> 16);
}
static __device__ __forceinline__ uint32_t pk2(float lo, float hi) {
    return (uint32_t)f2bf(lo) | ((uint32_t)f2bf(hi) << 16);
}
// async global->LDS, 16B per lane. LDS dest is wave-uniform base + lane*16.
static __device__ __forceinline__ void gload16(const uint16_t* g, uint16_t* l) {
    __builtin_amdgcn_global_load_lds((const __attribute__((address_space(1))) void*)g,
                                     (__attribute__((address_space(3))) void*)l, 16, 0, 0);
}

// ---------------------------------------------------------------------------
// Kernel 0: f32 row-major -> bf16 PK cast, all three X inputs in one dispatch.
// Destinations are DISJOINT (XqB in d_out, XkB/XvB in the dead S region).
// ---------------------------------------------------------------------------
__global__ __launch_bounds__(256) void cast3_bf16_pk(const float* __restrict__ x0,
                                                     const float* __restrict__ x1,
                                                     const float* __restrict__ x2,
                                                     uint16_t* __restrict__ d0,
                                                     uint16_t* __restrict__ d1,
                                                     uint16_t* __restrict__ d2) {
    const int z = blockIdx.y;
    const float* src = z == 0 ? x0 : (z == 1 ? x1 : x2);
    uint16_t* dst = z == 0 ? d0 : (z == 1 ? d1 : d2);
    const size_t c = (size_t)blockIdx.x * 256 + threadIdx.x;  // PK chunk id
    const size_t panel = c >> 11;           // 2048 chunks per 16x1024 panel
    const int w = (int)(c & 2047);
    const int ks = w >> 4, r15 = w & 15;
    const float* s = src + (panel * 16 + r15) * DMODEL + ks * 8;
    f32x4 a = *(const f32x4*)s;
    f32x4 b = *(const f32x4*)(s + 4);
    u32x4 o = {pk2(a[0], a[1]), pk2(a[2], a[3]), pk2(b[0], b[1]), pk2(b[2], b[3])};
    *(u32x4*)(dst + c * 8) = o;
}

// ---------------------------------------------------------------------------
// Kernel 1: cast + transpose weights into PK.  WT_pk(n,k) = W[k][n].
// ---------------------------------------------------------------------------
__global__ void wt_cast_kernel(const float* __restrict__ Wk, const float* __restrict__ Wv,
                               const float* __restrict__ Wq, uint16_t* __restrict__ WT) {
    const float* W = blockIdx.z == 0 ? Wk : (blockIdx.z == 1 ? Wv : Wq);
    uint16_t* dst = WT + (size_t)blockIdx.z * DMODEL * DMODEL;
    __shared__ float tile[32][33];
    const int x = blockIdx.x * 32, y = blockIdx.y * 32;
    const int tx = threadIdx.x, ty = threadIdx.y;
#pragma unroll
    for (int j = 0; j < 4; j++)
        tile[ty * 4 + j][tx] = W[(size_t)(y + ty * 4 + j) * DMODEL + x + tx];
    __syncthreads();
#pragma unroll
    for (int j = 0; j < 4; j++) {
        const int n = x + ty * 4 + j, k = y + tx;
        const size_t off = ((size_t)(n >> 4) * (DMODEL / 8) + (k >> 3)) * 128 +
                           (n & 15) * 8 + (k & 7);
        dst[off] = f2bf(tile[tx][ty * 4 + j]);
    }
}

// ---------------------------------------------------------------------------
// Kernel 2: DEEP-PIPELINED 256x256 B^T GEMM, BK=64, 8 waves (2M x 4N),
// 160 KB LDS: As[3 slots] (A staged 2 K-tiles ahead) + Bs[2 slots], PK ops,
// 32x32x16 MFMA core.   C[b][m][n] = sum_k A[b][m][k] * Bt[b][n][k]
// Per wave: 128x64 output = 4 row-tiles x 2 col-tiles of 32x32, acc 8xf32x16.
// 1 K-tile per iteration, 4 phases (phase q = K-step q, k = kt*64 + q*16):
//   pre : READ_B(sb)  (8 ds_read_b128: 2 ct x 4 kstep)
//   ph1 : 4 A-reads (rt x kstep0) | STG B(kt+1)h0 -> Bs[sb^1] | lgkm0 | 8 MFMA
//   ph2 : kstep1                  | STG B(kt+1)h1             | lgkm0 | 8 MFMA
//   ph3 : kstep2                  | STG A(kt+2)h0 -> As[sa2]  | lgkm0 | 8 MFMA
//   ph4 : kstep3 | STG A(kt+2)h1 | vmcnt(4) | BAR | lgkm0 | 8 MFMA | BAR
// Scheduling/slot/vmcnt ledger identical to r13 (verified bit-exact there).
// MODE 0: bf16 C in PK * scale. MODE 1: bf16 VT store (PK over [e][s]).
// MODE 2: f32 plain C * Linv[row].  MODE 3: merged QKV projection.
// BX=1: batch on blockIdx.x (XCD=batch).
// ---------------------------------------------------------------------------
#define STG_A(kt, sl, h)                                                          \
    do {                                                                          \
        const size_t g0 = (size_t)((h) * 8 + (tid >> 7)) * eldA +                 \
                          (size_t)(kt) * 1024 + (tid & 127) * 8;                  \
        gload16(Ab + g0, &As[sl][(h) * 8192 + tid * 8]);                          \
        gload16(Ab + g0 + 4 * eldA, &As[sl][(h) * 8192 + tid * 8 + 4096]);        \
    } while (0)
#define STG_B(kt, sl, h)                                                          \
    do {                                                                          \
        const size_t g0 = (size_t)((h) * 8 + (tid >> 7)) * eldB +                 \
                          (size_t)(kt) * 1024 + (tid & 127) * 8;                  \
        gload16(Bb + g0, &Bs[sl][(h) * 8192 + tid * 8]);                          \
        gload16(Bb + g0 + 4 * eldB, &Bs[sl][(h) * 8192 + tid * 8 + 4096]);        \
    } while (0)

// B fragments: col-tile ct (32 cols), kstep ks: panel pair (wc*4 + ct*2).
#define READ_B(sl)                                                                \
    _Pragma("unroll") for (int ct = 0; ct < 2; ct++)                              \
        _Pragma("unroll") for (int ks = 0; ks < 4; ks++)                          \
            bfr[ct][ks] = *(const bf16x8*)&Bs[sl][(wc * 4 + ct * 2) * 1024 +      \
                                                  lb32 + ks * 256];

#define VM4 asm volatile("s_waitcnt vmcnt(4)" ::: "memory")
#define VM0 asm volatile("s_waitcnt vmcnt(0)" ::: "memory")
#define NOPW (void)0
#define NOST (void)0

#define MFMA_Q(q)                                                                 \
    __builtin_amdgcn_s_setprio(1);                                                \
    _Pragma("unroll") for (int rt = 0; rt < 4; rt++) {                            \
        acc[rt][0] = MFMA32(afr[rt], bfr[0][q], acc[rt][0]);                      \
        acc[rt][1] = MFMA32(afr[rt], bfr[1][q], acc[rt][1]);                      \
    }                                                                             \
    __builtin_amdgcn_s_setprio(0);

#define PH_FREE(sl, q, STG)                                                       \
    do {                                                                          \
        bf16x8 afr[4];                                                            \
        _Pragma("unroll") for (int rt = 0; rt < 4; rt++)                          \
            afr[rt] = *(const bf16x8*)&As[sl][(wr * 8 + rt * 2) * 1024 +          \
                                              lb32 + (q) * 256];                  \
        STG;                                                                      \
        asm volatile("s_waitcnt lgkmcnt(0)" ::: "memory");                        \
        __builtin_amdgcn_sched_barrier(0);                                        \
        MFMA_Q(q)                                                                 \
    } while (0)

#define PH_SYNC(sl, q, STG, WAIT)                                                 \
    do {                                                                          \
        bf16x8 afr[4];                                                            \
        _Pragma("unroll") for (int rt = 0; rt < 4; rt++)                          \
            afr[rt] = *(const bf16x8*)&As[sl][(wr * 8 + rt * 2) * 1024 +          \
                                              lb32 + (q) * 256];                  \
        STG;                                                                      \
        WAIT;                                                                     \
        __builtin_amdgcn_s_barrier();                                             \
        asm volatile("s_waitcnt lgkmcnt(0)" ::: "memory");                        \
        __builtin_amdgcn_sched_barrier(0);                                        \
        MFMA_Q(q)                                                                 \
        __builtin_amdgcn_s_barrier();                                             \
    } while (0)

template <int MODE, int BX>
__global__ __launch_bounds__(512, 2) void gemm8p(const uint16_t* __restrict__ Ag,
                                                 const uint16_t* __restrict__ Bg,
                                                 void* __restrict__ Cg,
                                                 const float* __restrict__ Linv,
                                                 float scale, int lda, int ldb, int ldc,
                                                 int nk, size_t sA, size_t sB, size_t sC,
                                                 const uint16_t* __restrict__ A2,
                                                 const uint16_t* __restrict__ A3,
                                                 void* __restrict__ C2,
                                                 void* __restrict__ C3) {
    __shared__ __align__(16) uint16_t As[3][16384];   // 96 KB (3-slot rotation)
    __shared__ __align__(16) uint16_t Bs[2][16384];   // 64 KB -> 160 KB total
    const int bz = BX ? blockIdx.x : blockIdx.z;
    const int bm = BX ? blockIdx.y : blockIdx.x;
    const int bn = BX ? blockIdx.z : blockIdx.y;
    const int m0 = bm * 256, n0 = bn * 256;
    const uint16_t *Abase, *Bbase;
    if constexpr (MODE == 3) {
        // merged projection: bz = 0(Q) / 1(K) / 2(V); WT order in memory: K,V,Q
        Abase = (bz == 0) ? Ag : (bz == 1) ? A2 : A3;
        Bbase = Bg + ((bz == 0) ? 2 * sB : (bz == 1) ? (size_t)0 : sB);
    } else {
        Abase = Ag + (size_t)bz * sA;
        Bbase = Bg + (size_t)bz * sB;
    }
    const uint16_t* Ab = Abase + (size_t)m0 * lda;  // PK panel base
    const uint16_t* Bb = Bbase + (size_t)n0 * ldb;
    const int tid = threadIdx.x, lane = tid & 63;
    const int wid = tid >> 6, wr = wid >> 2, wc = wid & 3;
    // 32x32 fragment base: lane l -> row l&31 (panel-pair offset), kslot l>>5
    const int lb32 = ((lane >> 4) & 1) * 1024 + (lane >> 5) * 128 + (lane & 15) * 8;
    const int hv = lane >> 5;           // 4*(lane>>5) in C/D row formula
    const int cl = lane & 31;           // C/D col
    const size_t eldA = (size_t)lda * 16, eldB = (size_t)ldb * 16;

    f32x16 acc[4][2] = {};
    bf16x8 bfr[2][4];
    // prologue: A(0)->As[0], B(0)->Bs[0], A(1)->As[1]; vmcnt(4) drains
    // A(0)+B(0), leaves A(1) in flight.
    STG_A(0, 0, 0); STG_A(0, 0, 1);
    STG_B(0, 0, 0); STG_B(0, 0, 1);
    STG_A(1, 1, 0); STG_A(1, 1, 1);
    VM4;
    __builtin_amdgcn_s_barrier();
    int sa = 0, sa2 = 2, sb = 0;   // sa=kt%3, sa2=(kt+2)%3, sb=kt&1
    for (int kt = 0; kt < nk - 2; ++kt) {
        READ_B(sb);
        PH_FREE(sa, 0, STG_B(kt + 1, sb ^ 1, 0));
        PH_FREE(sa, 1, STG_B(kt + 1, sb ^ 1, 1));
        PH_FREE(sa, 2, STG_A(kt + 2, sa2, 0));
        PH_SYNC(sa, 3, STG_A(kt + 2, sa2, 1), VM4);
        sa = (sa == 2) ? 0 : sa + 1;
        sa2 = (sa2 == 2) ? 0 : sa2 + 1;
        sb ^= 1;
    }
    // kt = nk-2: stage last B only; drain everything for the final tile.
    READ_B(sb);
    PH_FREE(sa, 0, STG_B(nk - 1, sb ^ 1, 0));
    PH_FREE(sa, 1, STG_B(nk - 1, sb ^ 1, 1));
    PH_FREE(sa, 2, NOST);
    PH_SYNC(sa, 3, NOST, VM0);
    sa = (sa == 2) ? 0 : sa + 1;
    sb ^= 1;
    // kt = nk-1: no staging, no vm wait.
    READ_B(sb);
    PH_FREE(sa, 0, NOST);
    PH_FREE(sa, 1, NOST);
    PH_FREE(sa, 2, NOST);
    PH_SYNC(sa, 3, NOST, NOPW);

    // C/D map: col = cl, row = (reg&3) + 8*(reg>>2) + 4*hv  (reg in [0,16))
    if constexpr (MODE == 0) {
        uint16_t* C = (uint16_t*)Cg + (size_t)bz * sC;
#pragma unroll
        for (int rt = 0; rt < 4; rt++)
#pragma unroll
            for (int ct = 0; ct < 2; ct++)
#pragma unroll
                for (int g = 0; g < 4; g++) {
                    const int gm = m0 + wr * 128 + rt * 32 + g * 8 + hv * 4;
                    const int gn = n0 + wc * 64 + ct * 32 + cl;
                    const size_t off = ((size_t)(gm >> 4) * (ldc / 8) + (gn >> 3)) * 128 +
                                       (gm & 15) * 8 + (gn & 7);
#pragma unroll
                    for (int r = 0; r < 4; r++)
                        C[off + r * 8] = f2bf(acc[rt][ct][g * 4 + r] * scale);
                }
    } else if constexpr (MODE == 1) {
        uint16_t* C = (uint16_t*)Cg;
#pragma unroll
        for (int rt = 0; rt < 4; rt++)
#pragma unroll
            for (int ct = 0; ct < 2; ct++)
#pragma unroll
                for (int g = 0; g < 4; g++) {
                    const int gm = m0 + wr * 128 + rt * 32 + g * 8 + hv * 4;
                    const int bb = gm / SEQ;                 // uniform per block
                    const int s0 = gm - bb * SEQ;            // s0&7 in {0,4}
                    const int e = n0 + wc * 64 + ct * 32 + cl;
                    uint16_t* Cb = C + (size_t)bb * DMODEL * SEQ;
                    const size_t off = ((size_t)(e >> 4) * (SEQ / 8) + (s0 >> 3)) * 128 +
                                       (e & 15) * 8 + (s0 & 7);
                    u32x2 v = {pk2(acc[rt][ct][g * 4], acc[rt][ct][g * 4 + 1]),
                               pk2(acc[rt][ct][g * 4 + 2], acc[rt][ct][g * 4 + 3])};
                    *(u32x2*)&Cb[off] = v;
                }
    } else if constexpr (MODE == 2) {
        float* C = (float*)Cg + (size_t)bz * sC;
        const float* LB = Linv + bz * SEQ;
#pragma unroll
        for (int rt = 0; rt < 4; rt++)
#pragma unroll
            for (int ct = 0; ct < 2; ct++)
#pragma unroll
                for (int g = 0; g < 4; g++) {
                    const int gm = m0 + wr * 128 + rt * 32 + g * 8 + hv * 4;
                    const int gn = n0 + wc * 64 + ct * 32 + cl;
                    const f32x4 lv = *(const f32x4*)&LB[gm];
#pragma unroll
                    for (int r = 0; r < 4; r++)
                        C[(size_t)(gm + r) * ldc + gn] = acc[rt][ct][g * 4 + r] * lv[r];
                }
    } else {  // MODE 3: merged projection epilogue
        if (bz < 2) {
            uint16_t* C = (uint16_t*)(bz == 0 ? Cg : C2);
            const float sc = bz == 0 ? scale : 1.0f;
#pragma unroll
            for (int rt = 0; rt < 4; rt++)
#pragma unroll
                for (int ct = 0; ct < 2; ct++)
#pragma unroll
                    for (int g = 0; g < 4; g++) {
                        const int gm = m0 + wr * 128 + rt * 32 + g * 8 + hv * 4;
                        const int gn = n0 + wc * 64 + ct * 32 + cl;
                        const size_t off = ((size_t)(gm >> 4) * (ldc / 8) + (gn >> 3)) * 128 +
                                           (gm & 15) * 8 + (gn & 7);
#pragma unroll
                        for (int r = 0; r < 4; r++)
                            C[off + r * 8] = f2bf(acc[rt][ct][g * 4 + r] * sc);
                    }
        } else {
            uint16_t* C = (uint16_t*)C3;
#pragma unroll
            for (int rt = 0; rt < 4; rt++)
#pragma unroll
                for (int ct = 0; ct < 2; ct++)
#pragma unroll
                    for (int g = 0; g < 4; g++) {
                        const int gm = m0 + wr * 128 + rt * 32 + g * 8 + hv * 4;
                        const int bb = gm / SEQ;
                        const int s0 = gm - bb * SEQ;
                        const int e = n0 + wc * 64 + ct * 32 + cl;
                        uint16_t* Cb = C + (size_t)bb * DMODEL * SEQ;
                        const size_t off = ((size_t)(e >> 4) * (SEQ / 8) + (s0 >> 3)) * 128 +
                                           (e & 15) * 8 + (s0 & 7);
                        u32x2 v = {pk2(acc[rt][ct][g * 4], acc[rt][ct][g * 4 + 1]),
                                   pk2(acc[rt][ct][g * 4 + 2], acc[rt][ct][g * 4 + 3])};
                        *(u32x2*)&Cb[off] = v;
                    }
        }
    }
}

// ---------------------------------------------------------------------------
// Kernel 3: row softmax on PK-layout S, in place.  One block per 16-row panel
// (contiguous 32KB).  Thread t owns row t&15, k-slots (t>>4)+16u, u=0..15.
// ---------------------------------------------------------------------------
__global__ __launch_bounds__(256) void softmax_pk(uint16_t* __restrict__ S,
                                                  float* __restrict__ Linv) {
    const size_t panel = blockIdx.x;
    uint16_t* sp = S + panel * (size_t)(16 * SEQ);
    const int t = threadIdx.x, lane = t & 63, w = t >> 6;
    const int r15 = t & 15, ksl = t >> 4;
    __shared__ float rm[4][16], rs[4][16];
    u32x4 raw[16];
    float mx = -3.0e38f;
#pragma unroll
    for (int u = 0; u < 16; u++) {
        raw[u] = *(const u32x4*)&sp[(ksl + u * 16) * 128 + r15 * 8];
#pragma unroll
        for (int j = 0; j < 4; j++) {
            mx = fmaxf(mx, __builtin_bit_cast(float, raw[u][j] << 16));
            mx = fmaxf(mx, __builtin_bit_cast(float, raw[u][j] & 0xffff0000u));
        }
    }
    mx = fmaxf(mx, __shfl_xor(mx, 16));
    mx = fmaxf(mx, __shfl_xor(mx, 32));
    if (lane < 16) rm[w][lane] = mx;
    __syncthreads();
    const float m = fmaxf(fmaxf(rm[0][r15], rm[1][r15]), fmaxf(rm[2][r15], rm[3][r15]));
    float sum = 0.0f;
#pragma unroll
    for (int u = 0; u < 16; u++) {
#pragma unroll
        for (int j = 0; j < 4; j++) {
            float lo = __expf(__builtin_bit_cast(float, raw[u][j] << 16) - m);
            float hi = __expf(__builtin_bit_cast(float, raw[u][j] & 0xffff0000u) - m);
            sum += lo + hi;
            raw[u][j] = pk2(lo, hi);
        }
    }
    sum += __shfl_xor(sum, 16);
    sum += __shfl_xor(sum, 32);
    if (lane < 16) rs[w][lane] = sum;
    __syncthreads();
    const float tot = rs[0][r15] + rs[1][r15] + rs[2][r15] + rs[3][r15];
#pragma unroll
    for (int u = 0; u < 16; u++)
        *(u32x4*)&sp[(ksl + u * 16) * 128 + r15 * 8] = raw[u];
    if (w == 0 && lane < 16) Linv[panel * 16 + lane] = 1.0f / tot;
}

// ---------------------------------------------------------------------------
// Buffer plan (aliasing-audited):
//   ws:  Qbf [0, 33.5M)  Kbf [33.5M, 67.1M)  VTb [67.1M, 100.7M)
//        WT  [100.7M, 106.95M)  Linv [106.95M, ~107M)
//        S/P [107,020,288 .. 174,129,152)
//   X casts (all DISJOINT, dead before their region is re-written):
//        XqB = d_out[0 .. 32M)            (PV writes all of d_out at the end)
//        XkB = S + 0       [107,020,288)  (scores writes S after proj done)
//        XvB = S + 33.5MB  [140,574,720)
//   Temporal chain: cast3 -> proj(reads X*, writes Q/K/VT) -> scores(clobbers
//   XkB/XvB) -> softmax -> PV(clobbers XqB, writes full out).
// ---------------------------------------------------------------------------
extern "C" void kernel_launch(void* const* d_in, const int* in_sizes, int n_in,
                              void* d_out, int out_size, void* d_ws, size_t ws_size,
                              hipStream_t stream) {
    const float* Xk = (const float*)d_in[0];
    const float* Xv = (const float*)d_in[1];
    const float* Xq = (const float*)d_in[2];
    const float* Wk = (const float*)d_in[3];
    const float* Wv = (const float*)d_in[4];
    const float* Wq = (const float*)d_in[5];
    float* out = (float*)d_out;
    char* ws = (char*)d_ws;
    uint16_t* Qbf = (uint16_t*)(ws);
    uint16_t* Kbf = (uint16_t*)(ws + (size_t)33554432);
    uint16_t* VTb = (uint16_t*)(ws + (size_t)67108864);
    uint16_t* WT  = (uint16_t*)(ws + (size_t)100663296);
    float*    Linv= (float*)(ws + (size_t)106954752);
    uint16_t* Sb  = (uint16_t*)(ws + (size_t)107020288);
    uint16_t* XqB = (uint16_t*)d_out;                        // 32 MB of 64 MB out
    uint16_t* XkB = Sb;                                      // S + 0
    uint16_t* XvB = (uint16_t*)(ws + (size_t)140574720);     // S + 32 MB

    wt_cast_kernel<<<dim3(32, 32, 3), dim3(32, 8), 0, stream>>>(Wk, Wv, Wq, WT);
    // all three input casts in one dispatch (disjoint destinations)
    cast3_bf16_pk<<<dim3(8192, 3), 256, 0, stream>>>(Xq, Xk, Xv, XqB, XkB, XvB);
    // merged Q/K/V projection: z=0 Q (scale 1/32), z=1 K, z=2 V (VT store)
    gemm8p<3, 0><<<dim3(64, 4, 3), 512, 0, stream>>>(
        XqB, WT, (void*)Qbf, nullptr, 0.03125f,
        DMODEL, DMODEL, DMODEL, DMODEL / 64,
        0, (size_t)1048576 /*WT stride*/, 0,
        XkB, XvB, (void*)Kbf, (void*)VTb);
    // scores: S[b][q][k] = Qhat[b] . K[b]^T  (bf16 PK store), XCD = batch
    gemm8p<0, 1><<<dim3(8, 8, 8), 512, 0, stream>>>(
        Qbf, Kbf, (void*)Sb, nullptr, 1.0f,
        DMODEL, DMODEL, SEQ, DMODEL / 64,
        (size_t)SEQ * DMODEL, (size_t)SEQ * DMODEL, (size_t)SEQ * SEQ,
        nullptr, nullptr, nullptr, nullptr);
    // in-place row softmax -> P, Linv
    softmax_pk<<<dim3(BATCH * SEQ / 16), 256, 0, stream>>>(Sb, Linv);
    // Z[b][q][e] = (P[b] . V[b]) * Linv  (f32 plain store)
    gemm8p<2, 1><<<dim3(8, 8, 4), 512, 0, stream>>>(
        Sb, VTb, (void*)out, Linv, 1.0f,
        SEQ, SEQ, DMODEL, SEQ / 64,
        (size_t)SEQ * SEQ, (size_t)DMODEL * SEQ, (size_t)SEQ * DMODEL,
        nullptr, nullptr, nullptr, nullptr);
}

// Round 15
// 358.229 us; speedup vs baseline: 1.0225x; 1.0225x over previous
//
#include <hip/hip_runtime.h>
#include <hip/hip_bf16.h>
#include <stdint.h>

#define BATCH 8
#define SEQ 2048
#define DMODEL 1024

typedef __attribute__((ext_vector_type(4))) float f32x4;
typedef __attribute__((ext_vector_type(8))) short bf16x8;
typedef __attribute__((ext_vector_type(4))) uint32_t u32x4;
typedef __attribute__((ext_vector_type(2))) uint32_t u32x2;

#define MFMA16(a, b, c) __builtin_amdgcn_mfma_f32_16x16x32_bf16((a), (b), (c), 0, 0, 0)

// ---------------------------------------------------------------------------
// PK ("panel-k-major") operand layout for ALL bf16 GEMM operands:
//   elem(r,k) at offset (r>>4)*(Kd*16) + (k>>3)*128 + (r&15)*8 + (k&7)
//  * staging is contiguous + lane-linear in LDS (global_load_lds-legal);
//  * fragment ds_read_b128 is lane-linear -> zero bank conflicts.
// ---------------------------------------------------------------------------

static __device__ __forceinline__ uint16_t f2bf(float f) {
    uint32_t u = __builtin_bit_cast(uint32_t, f);
    u += 0x7fffu + ((u >> 16) & 1u);   // round-to-nearest-even
    return (uint16_t)(u >> 16);
}
static __device__ __forceinline__ uint32_t pk2(float lo, float hi) {
    return (uint32_t)f2bf(lo) | ((uint32_t)f2bf(hi) << 16);
}
// async global->LDS, 16B per lane. LDS dest is wave-uniform base + lane*16.
static __device__ __forceinline__ void gload16(const uint16_t* g, uint16_t* l) {
    __builtin_amdgcn_global_load_lds((const __attribute__((address_space(1))) void*)g,
                                     (__attribute__((address_space(3))) void*)l, 16, 0, 0);
}

// ---------------------------------------------------------------------------
// Kernel 0: f32 row-major -> bf16 PK cast, all three X inputs in one dispatch.
// Destinations are DISJOINT (XqB in d_out, XkB/XvB in the dead S region).
// ---------------------------------------------------------------------------
__global__ __launch_bounds__(256) void cast3_bf16_pk(const float* __restrict__ x0,
                                                     const float* __restrict__ x1,
                                                     const float* __restrict__ x2,
                                                     uint16_t* __restrict__ d0,
                                                     uint16_t* __restrict__ d1,
                                                     uint16_t* __restrict__ d2) {
    const int z = blockIdx.y;
    const float* src = z == 0 ? x0 : (z == 1 ? x1 : x2);
    uint16_t* dst = z == 0 ? d0 : (z == 1 ? d1 : d2);
    const size_t c = (size_t)blockIdx.x * 256 + threadIdx.x;  // PK chunk id
    const size_t panel = c >> 11;           // 2048 chunks per 16x1024 panel
    const int w = (int)(c & 2047);
    const int ks = w >> 4, r15 = w & 15;
    const float* s = src + (panel * 16 + r15) * DMODEL + ks * 8;
    f32x4 a = *(const f32x4*)s;
    f32x4 b = *(const f32x4*)(s + 4);
    u32x4 o = {pk2(a[0], a[1]), pk2(a[2], a[3]), pk2(b[0], b[1]), pk2(b[2], b[3])};
    *(u32x4*)(dst + c * 8) = o;
}

// ---------------------------------------------------------------------------
// Kernel 1: cast + transpose weights into PK.  WT_pk(n,k) = W[k][n].
// ---------------------------------------------------------------------------
__global__ void wt_cast_kernel(const float* __restrict__ Wk, const float* __restrict__ Wv,
                               const float* __restrict__ Wq, uint16_t* __restrict__ WT) {
    const float* W = blockIdx.z == 0 ? Wk : (blockIdx.z == 1 ? Wv : Wq);
    uint16_t* dst = WT + (size_t)blockIdx.z * DMODEL * DMODEL;
    __shared__ float tile[32][33];
    const int x = blockIdx.x * 32, y = blockIdx.y * 32;
    const int tx = threadIdx.x, ty = threadIdx.y;
#pragma unroll
    for (int j = 0; j < 4; j++)
        tile[ty * 4 + j][tx] = W[(size_t)(y + ty * 4 + j) * DMODEL + x + tx];
    __syncthreads();
#pragma unroll
    for (int j = 0; j < 4; j++) {
        const int n = x + ty * 4 + j, k = y + tx;
        const size_t off = ((size_t)(n >> 4) * (DMODEL / 8) + (k >> 3)) * 128 +
                           (n & 15) * 8 + (k & 7);
        dst[off] = f2bf(tile[tx][ty * 4 + j]);
    }
}

// ---------------------------------------------------------------------------
// Kernel 2: 2-RESIDENT-BLOCK 256x128 B^T GEMM, BK=32, 8 waves (4M x 2N),
// per-wave 64x64 (acc = 4x4 f32x4 = 64 AGPR), 48 KB LDS 2-slot dbuf,
// __launch_bounds__(512,4) -> 128-reg cap -> 2 independent blocks/CU
// (4 waves/SIMD): one block's vmcnt/barrier stalls are covered by the other
// block's MFMA (m114 mechanism — unavailable in all prior 256/128-reg
// configs whose acc alone was 128 AGPR).
//   C[b][m][n] = sum_k A[b][m][k] * Bt[b][n][k]
// Per K-tile: {STG next (3 gload) -> vmcnt(3) -> BAR -> 4 A + 4 B ds_read_b128
// -> lgkm0 -> 16 MFMA (setprio) -> BAR}.  vmcnt(3)@iter kt drains the slot
// about to be read (staged iter kt-1), keeps this iter's 3 stages in flight.
// Slot overwrite (sb^1) is protected by the end-barrier of iter kt-1.
// K-order per acc: kt ascending, one 16x16x32 per K-tile — identical math
// order to prior rounds (bit-identical output).
// MODE 0: bf16 C in PK * scale. MODE 1: bf16 VT store (PK over [e][s]).
// MODE 2: f32 plain C * Linv[row].  MODE 3: merged QKV projection.
// BX=1: batch on blockIdx.x (XCD=batch).
// ---------------------------------------------------------------------------
#define STG(kt, sl)                                                               \
    do {                                                                          \
        const size_t k0_ = (size_t)(kt) * 512;                                    \
        gload16(Ab + k0_ + sA0, &As[sl][tid * 8]);                                \
        gload16(Ab + k0_ + sA1, &As[sl][tid * 8 + 4096]);                         \
        gload16(Bb + k0_ + sB0, &Bs[sl][tid * 8]);                                \
    } while (0)

#define VM3 asm volatile("s_waitcnt vmcnt(3)" ::: "memory")
#define VM0 asm volatile("s_waitcnt vmcnt(0)" ::: "memory")

#define KTILE_BODY(sl)                                                            \
    do {                                                                          \
        bf16x8 af[4], bf[4];                                                      \
        _Pragma("unroll") for (int i = 0; i < 4; i++)                             \
            af[i] = *(const bf16x8*)&As[sl][(wr * 4 + i) * 512 + lbase];          \
        _Pragma("unroll") for (int j = 0; j < 4; j++)                             \
            bf[j] = *(const bf16x8*)&Bs[sl][(wc * 4 + j) * 512 + lbase];          \
        asm volatile("s_waitcnt lgkmcnt(0)" ::: "memory");                        \
        __builtin_amdgcn_sched_barrier(0);                                        \
        __builtin_amdgcn_s_setprio(1);                                            \
        _Pragma("unroll") for (int i = 0; i < 4; i++)                             \
            _Pragma("unroll") for (int j = 0; j < 4; j++)                         \
                acc[i][j] = MFMA16(af[i], bf[j], acc[i][j]);                      \
        __builtin_amdgcn_s_setprio(0);                                            \
    } while (0)

template <int MODE, int BX>
__global__ __launch_bounds__(512, 4) void gemm2b(const uint16_t* __restrict__ Ag,
                                                 const uint16_t* __restrict__ Bg,
                                                 void* __restrict__ Cg,
                                                 const float* __restrict__ Linv,
                                                 float scale, int lda, int ldb, int ldc,
                                                 int nk, size_t sA, size_t sB, size_t sC,
                                                 const uint16_t* __restrict__ A2,
                                                 const uint16_t* __restrict__ A3,
                                                 void* __restrict__ C2,
                                                 void* __restrict__ C3) {
    __shared__ __align__(16) uint16_t As[2][8192];   // 2 x 16 KB
    __shared__ __align__(16) uint16_t Bs[2][4096];   // 2 x 8 KB  -> 48 KB total
    const int bz = BX ? blockIdx.x : blockIdx.z;
    const int bm = BX ? blockIdx.y : blockIdx.x;
    const int bn = BX ? blockIdx.z : blockIdx.y;
    const int m0 = bm * 256, n0 = bn * 128;
    const uint16_t *Abase, *Bbase;
    if constexpr (MODE == 3) {
        // merged projection: bz = 0(Q) / 1(K) / 2(V); WT order in memory: K,V,Q
        Abase = (bz == 0) ? Ag : (bz == 1) ? A2 : A3;
        Bbase = Bg + ((bz == 0) ? 2 * sB : (bz == 1) ? (size_t)0 : sB);
    } else {
        Abase = Ag + (size_t)bz * sA;
        Bbase = Bg + (size_t)bz * sB;
    }
    const uint16_t* Ab = Abase + (size_t)m0 * lda;  // PK panel base
    const uint16_t* Bb = Bbase + (size_t)n0 * ldb;
    const int tid = threadIdx.x, lane = tid & 63;
    const int wid = tid >> 6, wr = wid >> 1, wc = wid & 1;
    const int lr = lane & 15, lg = lane >> 4;
    const int lbase = lg * 128 + lr * 8;
    const size_t eldA = (size_t)lda * 16, eldB = (size_t)ldb * 16;
    // staging: A panels 0-7 (chunk tid) + 8-15 (chunk tid+512); B panels 0-7.
    const size_t sA0 = (size_t)(tid >> 6) * eldA + (tid & 63) * 8;
    const size_t sA1 = sA0 + 8 * eldA;
    const size_t sB0 = (size_t)(tid >> 6) * eldB + (tid & 63) * 8;

    f32x4 acc[4][4] = {};
    // prologue: tile 0 staged, fully drained.
    STG(0, 0);
    VM0;
    __builtin_amdgcn_s_barrier();
    int sb = 0;
    for (int kt = 0; kt < nk - 1; ++kt) {
        STG(kt + 1, sb ^ 1);      // +3 (slot sb^1 free: end-bar of kt-1)
        VM3;                      // drains tile kt (staged last iter)
        __builtin_amdgcn_s_barrier();   // all waves' tile-kt stages landed
        KTILE_BODY(sb);
        __builtin_amdgcn_s_barrier();   // reads of sb done -> sb writable next
        sb ^= 1;
    }
    // final tile: drain its 3 in-flight stages, no further staging.
    VM0;
    __builtin_amdgcn_s_barrier();
    KTILE_BODY(sb);

    // epilogue: gm = m0 + wr*64 + i*16 + lg*4 ; gn = n0 + wc*64 + j*16 + lr
    if constexpr (MODE == 0) {
        uint16_t* C = (uint16_t*)Cg + (size_t)bz * sC;
#pragma unroll
        for (int i = 0; i < 4; i++) {
            const int gm = m0 + wr * 64 + i * 16 + lg * 4;   // gm&15 == lg*4
            const size_t pbase = (size_t)(gm >> 4) * (ldc / 8);
#pragma unroll
            for (int j = 0; j < 4; j++) {
                const int gn = n0 + wc * 64 + j * 16 + lr;
                const size_t off = (pbase + (gn >> 3)) * 128 + (gn & 7);
#pragma unroll
                for (int r = 0; r < 4; r++)
                    C[off + (lg * 4 + r) * 8] = f2bf(acc[i][j][r] * scale);
            }
        }
    } else if constexpr (MODE == 1) {
        uint16_t* C = (uint16_t*)Cg;
#pragma unroll
        for (int i = 0; i < 4; i++) {
            const int gm = m0 + wr * 64 + i * 16 + lg * 4;   // global m = b*SEQ + s
            const int bb = gm / SEQ;                         // uniform per block
            const int s0 = gm - bb * SEQ;                    // s0&7 in {0,4}
            uint16_t* Cb = C + (size_t)bb * DMODEL * SEQ;
#pragma unroll
            for (int j = 0; j < 4; j++) {
                const int e = n0 + wc * 64 + j * 16 + lr;
                const size_t off = ((size_t)(e >> 4) * (SEQ / 8) + (s0 >> 3)) * 128 +
                                   (e & 15) * 8 + (s0 & 7);
                u32x2 v = {pk2(acc[i][j][0], acc[i][j][1]), pk2(acc[i][j][2], acc[i][j][3])};
                *(u32x2*)&Cb[off] = v;
            }
        }
    } else if constexpr (MODE == 2) {
        float* C = (float*)Cg + (size_t)bz * sC;
        const float* LB = Linv + bz * SEQ;
#pragma unroll
        for (int i = 0; i < 4; i++) {
            const int gm = m0 + wr * 64 + i * 16 + lg * 4;
            const f32x4 lv = *(const f32x4*)&LB[gm];
#pragma unroll
            for (int j = 0; j < 4; j++) {
                const int gn = n0 + wc * 64 + j * 16 + lr;
#pragma unroll
                for (int r = 0; r < 4; r++)
                    C[(size_t)(gm + r) * ldc + gn] = acc[i][j][r] * lv[r];
            }
        }
    } else {  // MODE 3: merged projection epilogue
        if (bz < 2) {
            uint16_t* C = (uint16_t*)(bz == 0 ? Cg : C2);
            const float sc = bz == 0 ? scale : 1.0f;
#pragma unroll
            for (int i = 0; i < 4; i++) {
                const int gm = m0 + wr * 64 + i * 16 + lg * 4;
                const size_t pbase = (size_t)(gm >> 4) * (ldc / 8);
#pragma unroll
                for (int j = 0; j < 4; j++) {
                    const int gn = n0 + wc * 64 + j * 16 + lr;
                    const size_t off = (pbase + (gn >> 3)) * 128 + (gn & 7);
#pragma unroll
                    for (int r = 0; r < 4; r++)
                        C[off + (lg * 4 + r) * 8] = f2bf(acc[i][j][r] * sc);
                }
            }
        } else {
            uint16_t* C = (uint16_t*)C3;
#pragma unroll
            for (int i = 0; i < 4; i++) {
                const int gm = m0 + wr * 64 + i * 16 + lg * 4;
                const int bb = gm / SEQ;
                const int s0 = gm - bb * SEQ;
                uint16_t* Cb = C + (size_t)bb * DMODEL * SEQ;
#pragma unroll
                for (int j = 0; j < 4; j++) {
                    const int e = n0 + wc * 64 + j * 16 + lr;
                    const size_t off = ((size_t)(e >> 4) * (SEQ / 8) + (s0 >> 3)) * 128 +
                                       (e & 15) * 8 + (s0 & 7);
                    u32x2 v = {pk2(acc[i][j][0], acc[i][j][1]),
                               pk2(acc[i][j][2], acc[i][j][3])};
                    *(u32x2*)&Cb[off] = v;
                }
            }
        }
    }
}

// ---------------------------------------------------------------------------
// Kernel 3: row softmax on PK-layout S, in place.  One block per 16-row panel
// (contiguous 32KB).  Thread t owns row t&15, k-slots (t>>4)+16u, u=0..15.
// ---------------------------------------------------------------------------
__global__ __launch_bounds__(256) void softmax_pk(uint16_t* __restrict__ S,
                                                  float* __restrict__ Linv) {
    const size_t panel = blockIdx.x;
    uint16_t* sp = S + panel * (size_t)(16 * SEQ);
    const int t = threadIdx.x, lane = t & 63, w = t >> 6;
    const int r15 = t & 15, ksl = t >> 4;
    __shared__ float rm[4][16], rs[4][16];
    u32x4 raw[16];
    float mx = -3.0e38f;
#pragma unroll
    for (int u = 0; u < 16; u++) {
        raw[u] = *(const u32x4*)&sp[(ksl + u * 16) * 128 + r15 * 8];
#pragma unroll
        for (int j = 0; j < 4; j++) {
            mx = fmaxf(mx, __builtin_bit_cast(float, raw[u][j] << 16));
            mx = fmaxf(mx, __builtin_bit_cast(float, raw[u][j] & 0xffff0000u));
        }
    }
    mx = fmaxf(mx, __shfl_xor(mx, 16));
    mx = fmaxf(mx, __shfl_xor(mx, 32));
    if (lane < 16) rm[w][lane] = mx;
    __syncthreads();
    const float m = fmaxf(fmaxf(rm[0][r15], rm[1][r15]), fmaxf(rm[2][r15], rm[3][r15]));
    float sum = 0.0f;
#pragma unroll
    for (int u = 0; u < 16; u++) {
#pragma unroll
        for (int j = 0; j < 4; j++) {
            float lo = __expf(__builtin_bit_cast(float, raw[u][j] << 16) - m);
            float hi = __expf(__builtin_bit_cast(float, raw[u][j] & 0xffff0000u) - m);
            sum += lo + hi;
            raw[u][j] = pk2(lo, hi);
        }
    }
    sum += __shfl_xor(sum, 16);
    sum += __shfl_xor(sum, 32);
    if (lane < 16) rs[w][lane] = sum;
    __syncthreads();
    const float tot = rs[0][r15] + rs[1][r15] + rs[2][r15] + rs[3][r15];
#pragma unroll
    for (int u = 0; u < 16; u++)
        *(u32x4*)&sp[(ksl + u * 16) * 128 + r15 * 8] = raw[u];
    if (w == 0 && lane < 16) Linv[panel * 16 + lane] = 1.0f / tot;
}

// ---------------------------------------------------------------------------
// Buffer plan (aliasing-audited):
//   ws:  Qbf [0, 33.5M)  Kbf [33.5M, 67.1M)  VTb [67.1M, 100.7M)
//        WT  [100.7M, 106.95M)  Linv [106.95M, ~107M)
//        S/P [107,020,288 .. 174,129,152)
//   X casts (all DISJOINT, dead before their region is re-written):
//        XqB = d_out[0 .. 32M)            (PV writes all of d_out at the end)
//        XkB = S + 0       [107,020,288)  (scores writes S after proj done)
//        XvB = S + 33.5MB  [140,574,720)
//   Temporal chain: cast3 -> proj(reads X*, writes Q/K/VT) -> scores(clobbers
//   XkB/XvB) -> softmax -> PV(clobbers XqB, writes full out).
// ---------------------------------------------------------------------------
extern "C" void kernel_launch(void* const* d_in, const int* in_sizes, int n_in,
                              void* d_out, int out_size, void* d_ws, size_t ws_size,
                              hipStream_t stream) {
    const float* Xk = (const float*)d_in[0];
    const float* Xv = (const float*)d_in[1];
    const float* Xq = (const float*)d_in[2];
    const float* Wk = (const float*)d_in[3];
    const float* Wv = (const float*)d_in[4];
    const float* Wq = (const float*)d_in[5];
    float* out = (float*)d_out;
    char* ws = (char*)d_ws;
    uint16_t* Qbf = (uint16_t*)(ws);
    uint16_t* Kbf = (uint16_t*)(ws + (size_t)33554432);
    uint16_t* VTb = (uint16_t*)(ws + (size_t)67108864);
    uint16_t* WT  = (uint16_t*)(ws + (size_t)100663296);
    float*    Linv= (float*)(ws + (size_t)106954752);
    uint16_t* Sb  = (uint16_t*)(ws + (size_t)107020288);
    uint16_t* XqB = (uint16_t*)d_out;                        // 32 MB of 64 MB out
    uint16_t* XkB = Sb;                                      // S + 0
    uint16_t* XvB = (uint16_t*)(ws + (size_t)140574720);     // S + 32 MB

    wt_cast_kernel<<<dim3(32, 32, 3), dim3(32, 8), 0, stream>>>(Wk, Wv, Wq, WT);
    // all three input casts in one dispatch (disjoint destinations)
    cast3_bf16_pk<<<dim3(8192, 3), 256, 0, stream>>>(Xq, Xk, Xv, XqB, XkB, XvB);
    // merged Q/K/V projection: z=0 Q (scale 1/32), z=1 K, z=2 V (VT store)
    gemm2b<3, 0><<<dim3(64, 8, 3), 512, 0, stream>>>(
        XqB, WT, (void*)Qbf, nullptr, 0.03125f,
        DMODEL, DMODEL, DMODEL, DMODEL / 32,
        0, (size_t)1048576 /*WT stride*/, 0,
        XkB, XvB, (void*)Kbf, (void*)VTb);
    // scores: S[b][q][k] = Qhat[b] . K[b]^T  (bf16 PK store), XCD = batch
    gemm2b<0, 1><<<dim3(8, 8, 16), 512, 0, stream>>>(
        Qbf, Kbf, (void*)Sb, nullptr, 1.0f,
        DMODEL, DMODEL, SEQ, DMODEL / 32,
        (size_t)SEQ * DMODEL, (size_t)SEQ * DMODEL, (size_t)SEQ * SEQ,
        nullptr, nullptr, nullptr, nullptr);
    // in-place row softmax -> P, Linv
    softmax_pk<<<dim3(BATCH * SEQ / 16), 256, 0, stream>>>(Sb, Linv);
    // Z[b][q][e] = (P[b] . V[b]) * Linv  (f32 plain store)
    gemm2b<2, 1><<<dim3(8, 8, 8), 512, 0, stream>>>(
        Sb, VTb, (void*)out, Linv, 1.0f,
        SEQ, SEQ, DMODEL, SEQ / 32,
        (size_t)SEQ * SEQ, (size_t)DMODEL * SEQ, (size_t)SEQ * DMODEL,
        nullptr, nullptr, nullptr, nullptr);
}

// Round 16
// 339.094 us; speedup vs baseline: 1.0802x; 1.0564x over previous
//
#include <hip/hip_runtime.h>
#include <hip/hip_bf16.h>
#include <stdint.h>

#define BATCH 8
#define SEQ 2048
#define DMODEL 1024

typedef __attribute__((ext_vector_type(4))) float f32x4;
typedef __attribute__((ext_vector_type(8))) short bf16x8;
typedef __attribute__((ext_vector_type(4))) uint32_t u32x4;
typedef __attribute__((ext_vector_type(2))) uint32_t u32x2;

#define MFMA16(a, b, c) __builtin_amdgcn_mfma_f32_16x16x32_bf16((a), (b), (c), 0, 0, 0)

// ---------------------------------------------------------------------------
// PK ("panel-k-major") operand layout for ALL bf16 GEMM operands:
//   elem(r,k) at offset (r>>4)*(Kd*16) + (k>>3)*128 + (r&15)*8 + (k&7)
//  * staging is contiguous + lane-linear in LDS (global_load_lds-legal);
//  * fragment ds_read_b128 is lane-linear -> zero bank conflicts.
// ---------------------------------------------------------------------------

static __device__ __forceinline__ uint16_t f2bf(float f) {
    uint32_t u = __builtin_bit_cast(uint32_t, f);
    u += 0x7fffu + ((u >> 16) & 1u);   // round-to-nearest-even
    return (uint16_t)(u >> 16);
}
static __device__ __forceinline__ uint32_t pk2(float lo, float hi) {
    return (uint32_t)f2bf(lo) | ((uint32_t)f2bf(hi) << 16);
}
// async global->LDS, 16B per lane. LDS dest is wave-uniform base + lane*16.
static __device__ __forceinline__ void gload16(const uint16_t* g, uint16_t* l) {
    __builtin_amdgcn_global_load_lds((const __attribute__((address_space(1))) void*)g,
                                     (__attribute__((address_space(3))) void*)l, 16, 0, 0);
}

// ---------------------------------------------------------------------------
// Kernel 0: f32 row-major -> bf16 PK cast, all three X inputs in one dispatch.
// Destinations are DISJOINT (XqB in d_out, XkB/XvB in the dead S region).
// ---------------------------------------------------------------------------
__global__ __launch_bounds__(256) void cast3_bf16_pk(const float* __restrict__ x0,
                                                     const float* __restrict__ x1,
                                                     const float* __restrict__ x2,
                                                     uint16_t* __restrict__ d0,
                                                     uint16_t* __restrict__ d1,
                                                     uint16_t* __restrict__ d2) {
    const int z = blockIdx.y;
    const float* src = z == 0 ? x0 : (z == 1 ? x1 : x2);
    uint16_t* dst = z == 0 ? d0 : (z == 1 ? d1 : d2);
    const size_t c = (size_t)blockIdx.x * 256 + threadIdx.x;  // PK chunk id
    const size_t panel = c >> 11;           // 2048 chunks per 16x1024 panel
    const int w = (int)(c & 2047);
    const int ks = w >> 4, r15 = w & 15;
    const float* s = src + (panel * 16 + r15) * DMODEL + ks * 8;
    f32x4 a = *(const f32x4*)s;
    f32x4 b = *(const f32x4*)(s + 4);
    u32x4 o = {pk2(a[0], a[1]), pk2(a[2], a[3]), pk2(b[0], b[1]), pk2(b[2], b[3])};
    *(u32x4*)(dst + c * 8) = o;
}

// ---------------------------------------------------------------------------
// Kernel 1: cast + transpose weights into PK.  WT_pk(n,k) = W[k][n].
// ---------------------------------------------------------------------------
__global__ void wt_cast_kernel(const float* __restrict__ Wk, const float* __restrict__ Wv,
                               const float* __restrict__ Wq, uint16_t* __restrict__ WT) {
    const float* W = blockIdx.z == 0 ? Wk : (blockIdx.z == 1 ? Wv : Wq);
    uint16_t* dst = WT + (size_t)blockIdx.z * DMODEL * DMODEL;
    __shared__ float tile[32][33];
    const int x = blockIdx.x * 32, y = blockIdx.y * 32;
    const int tx = threadIdx.x, ty = threadIdx.y;
#pragma unroll
    for (int j = 0; j < 4; j++)
        tile[ty * 4 + j][tx] = W[(size_t)(y + ty * 4 + j) * DMODEL + x + tx];
    __syncthreads();
#pragma unroll
    for (int j = 0; j < 4; j++) {
        const int n = x + ty * 4 + j, k = y + tx;
        const size_t off = ((size_t)(n >> 4) * (DMODEL / 8) + (k >> 3)) * 128 +
                           (n & 15) * 8 + (k & 7);
        dst[off] = f2bf(tile[tx][ty * 4 + j]);
    }
}

// ---------------------------------------------------------------------------
// Kernel 2: DEEP-PIPELINED 256x256 B^T GEMM, BK=64, 8 waves (2M x 4N),
// 160 KB LDS: As[3 slots] (A staged 2 K-tiles ahead) + Bs[2 slots], PK ops.
//   C[b][m][n] = sum_k A[b][m][k] * Bt[b][n][k]
// COMPILER-SCHEDULED phase bodies (r15 change): no explicit lgkmcnt(0) or
// sched_barrier(0) in the phases — the HIP compiler emits fine-grained
// counted lgkmcnt between each ds_read and its dependent MFMA (m97), letting
// tail-read latency hide under early MFMAs.  Zero-instruction compiler
// fences (asm "" memory) at barriers/vm-waits pin memory ORDER without
// pinning the instruction SCHEDULE (m141 lesson).
// 1 K-tile per iteration, 4 phases:
//   pre : READ_B(sb)  (8 ds_read_b128; B(kt), staged last iter)
//   ph1 : 4 A-reads q0 | STG B(kt+1)h0 -> Bs[sb^1] | 16 MFMA
//   ph2 : q1           | STG B(kt+1)h1             | 16 MFMA
//   ph3 : q2           | STG A(kt+2)h0 -> As[sa2]  | 16 MFMA
//   ph4 : q3           | STG A(kt+2)h1 | vmcnt(4) | BAR | 16 MFMA | BAR
// vmcnt(4)@ph4: outstanding = A(kt+1)[4] + B(kt+1)[4] + A(kt+2)[4] -> drain
// to 4 lands A(kt+1)+B(kt+1) (all of next iter's reads), keeps A(kt+2) flying.
// Slot ledger identical to r13 (verified bit-exact): every overwrite is
// barrier-separated from its last reader; every read's consumer (MFMA)
// precedes the end-barrier, so reads are drained before any wave overwrites.
// MODE 0: bf16 C in PK * scale. MODE 1: bf16 VT store (PK over [e][s]).
// MODE 2: f32 plain C * Linv[row].  MODE 3: merged QKV projection.
// BX=1: batch on blockIdx.x (XCD=batch).
// ---------------------------------------------------------------------------
#define STG_A(kt, sl, h)                                                          \
    do {                                                                          \
        const size_t g0 = (size_t)((h) * 8 + (tid >> 7)) * eldA +                 \
                          (size_t)(kt) * 1024 + (tid & 127) * 8;                  \
        gload16(Ab + g0, &As[sl][(h) * 8192 + tid * 8]);                          \
        gload16(Ab + g0 + 4 * eldA, &As[sl][(h) * 8192 + tid * 8 + 4096]);        \
    } while (0)
#define STG_B(kt, sl, h)                                                          \
    do {                                                                          \
        const size_t g0 = (size_t)((h) * 8 + (tid >> 7)) * eldB +                 \
                          (size_t)(kt) * 1024 + (tid & 127) * 8;                  \
        gload16(Bb + g0, &Bs[sl][(h) * 8192 + tid * 8]);                          \
        gload16(Bb + g0 + 4 * eldB, &Bs[sl][(h) * 8192 + tid * 8 + 4096]);        \
    } while (0)

#define READ_B(sl)                                                                \
    _Pragma("unroll") for (int j = 0; j < 4; j++) {                               \
        bfr[j][0] = *(const bf16x8*)&Bs[sl][(wc * 4 + j) * 1024 + lbase];         \
        bfr[j][1] = *(const bf16x8*)&Bs[sl][(wc * 4 + j) * 1024 + 512 + lbase];   \
    }

#define VM4 asm volatile("s_waitcnt vmcnt(4)" ::: "memory")
#define VM0 asm volatile("s_waitcnt vmcnt(0)" ::: "memory")
#define CFENCE asm volatile("" ::: "memory")
#define NOPW (void)0
#define NOST (void)0

#define MFMA_Q(q)                                                                 \
    __builtin_amdgcn_s_setprio(1);                                                \
    _Pragma("unroll") for (int j = 0; j < 4; j++) {                               \
        acc[2 * (q)][j] = MFMA16(a00, bfr[j][0], acc[2 * (q)][j]);                \
        acc[2 * (q)][j] = MFMA16(a01, bfr[j][1], acc[2 * (q)][j]);                \
        acc[2 * (q) + 1][j] = MFMA16(a10, bfr[j][0], acc[2 * (q) + 1][j]);        \
        acc[2 * (q) + 1][j] = MFMA16(a11, bfr[j][1], acc[2 * (q) + 1][j]);        \
    }                                                                             \
    __builtin_amdgcn_s_setprio(0);

#define PH_FREE(sl, q, STG)                                                       \
    do {                                                                          \
        const int ab = (wr * 8 + 2 * (q)) * 1024 + lbase;                         \
        bf16x8 a00 = *(const bf16x8*)&As[sl][ab];                                 \
        bf16x8 a01 = *(const bf16x8*)&As[sl][ab + 512];                           \
        bf16x8 a10 = *(const bf16x8*)&As[sl][ab + 1024];                          \
        bf16x8 a11 = *(const bf16x8*)&As[sl][ab + 1536];                          \
        STG;                                                                      \
        MFMA_Q(q)                                                                 \
    } while (0)

#define PH_SYNC(sl, q, STG, WAIT)                                                 \
    do {                                                                          \
        const int ab = (wr * 8 + 2 * (q)) * 1024 + lbase;                         \
        bf16x8 a00 = *(const bf16x8*)&As[sl][ab];                                 \
        bf16x8 a01 = *(const bf16x8*)&As[sl][ab + 512];                           \
        bf16x8 a10 = *(const bf16x8*)&As[sl][ab + 1024];                          \
        bf16x8 a11 = *(const bf16x8*)&As[sl][ab + 1536];                          \
        STG;                                                                      \
        WAIT;                                                                     \
        CFENCE;                                                                   \
        __builtin_amdgcn_s_barrier();                                             \
        CFENCE;                                                                   \
        MFMA_Q(q)                                                                 \
        CFENCE;                                                                   \
        __builtin_amdgcn_s_barrier();                                             \
        CFENCE;                                                                   \
    } while (0)

template <int MODE, int BX>
__global__ __launch_bounds__(512, 2) void gemm8p(const uint16_t* __restrict__ Ag,
                                                 const uint16_t* __restrict__ Bg,
                                                 void* __restrict__ Cg,
                                                 const float* __restrict__ Linv,
                                                 float scale, int lda, int ldb, int ldc,
                                                 int nk, size_t sA, size_t sB, size_t sC,
                                                 const uint16_t* __restrict__ A2,
                                                 const uint16_t* __restrict__ A3,
                                                 void* __restrict__ C2,
                                                 void* __restrict__ C3) {
    __shared__ __align__(16) uint16_t As[3][16384];   // 96 KB (3-slot rotation)
    __shared__ __align__(16) uint16_t Bs[2][16384];   // 64 KB -> 160 KB total
    const int bz = BX ? blockIdx.x : blockIdx.z;
    const int bm = BX ? blockIdx.y : blockIdx.x;
    const int bn = BX ? blockIdx.z : blockIdx.y;
    const int m0 = bm * 256, n0 = bn * 256;
    const uint16_t *Abase, *Bbase;
    if constexpr (MODE == 3) {
        // merged projection: bz = 0(Q) / 1(K) / 2(V); WT order in memory: K,V,Q
        Abase = (bz == 0) ? Ag : (bz == 1) ? A2 : A3;
        Bbase = Bg + ((bz == 0) ? 2 * sB : (bz == 1) ? (size_t)0 : sB);
    } else {
        Abase = Ag + (size_t)bz * sA;
        Bbase = Bg + (size_t)bz * sB;
    }
    const uint16_t* Ab = Abase + (size_t)m0 * lda;  // PK panel base
    const uint16_t* Bb = Bbase + (size_t)n0 * ldb;
    const int tid = threadIdx.x, lane = tid & 63;
    const int wid = tid >> 6, wr = wid >> 2, wc = wid & 3;
    const int lr = lane & 15, lg = lane >> 4;
    const int lbase = lg * 128 + lr * 8;
    const size_t eldA = (size_t)lda * 16, eldB = (size_t)ldb * 16;

    f32x4 acc[8][4] = {};
    bf16x8 bfr[4][2];
    // prologue: A(0)->As[0], B(0)->Bs[0], A(1)->As[1]; vmcnt(4) drains
    // A(0)+B(0), leaves A(1) in flight.
    STG_A(0, 0, 0); STG_A(0, 0, 1);
    STG_B(0, 0, 0); STG_B(0, 0, 1);
    STG_A(1, 1, 0); STG_A(1, 1, 1);
    VM4;
    CFENCE;
    __builtin_amdgcn_s_barrier();
    CFENCE;
    int sa = 0, sa2 = 2, sb = 0;   // sa=kt%3, sa2=(kt+2)%3, sb=kt&1
    for (int kt = 0; kt < nk - 2; ++kt) {
        READ_B(sb);
        PH_FREE(sa, 0, STG_B(kt + 1, sb ^ 1, 0));
        PH_FREE(sa, 1, STG_B(kt + 1, sb ^ 1, 1));
        PH_FREE(sa, 2, STG_A(kt + 2, sa2, 0));
        PH_SYNC(sa, 3, STG_A(kt + 2, sa2, 1), VM4);
        sa = (sa == 2) ? 0 : sa + 1;
        sa2 = (sa2 == 2) ? 0 : sa2 + 1;
        sb ^= 1;
    }
    // kt = nk-2: stage last B only; drain everything for the final tile.
    READ_B(sb);
    PH_FREE(sa, 0, STG_B(nk - 1, sb ^ 1, 0));
    PH_FREE(sa, 1, STG_B(nk - 1, sb ^ 1, 1));
    PH_FREE(sa, 2, NOST);
    PH_SYNC(sa, 3, NOST, VM0);
    sa = (sa == 2) ? 0 : sa + 1;
    sb ^= 1;
    // kt = nk-1: no staging, no vm wait.
    READ_B(sb);
    PH_FREE(sa, 0, NOST);
    PH_FREE(sa, 1, NOST);
    PH_FREE(sa, 2, NOST);
    PH_SYNC(sa, 3, NOST, NOPW);

    if constexpr (MODE == 0) {
        uint16_t* C = (uint16_t*)Cg + (size_t)bz * sC;
#pragma unroll
        for (int i = 0; i < 8; i++) {
            const int gm = m0 + wr * 128 + i * 16 + lg * 4;   // gm&15 == lg*4
            const size_t pbase = (size_t)(gm >> 4) * (ldc / 8);
#pragma unroll
            for (int j = 0; j < 4; j++) {
                const int gn = n0 + wc * 64 + j * 16 + lr;
                const size_t off = (pbase + (gn >> 3)) * 128 + (gn & 7);
#pragma unroll
                for (int r = 0; r < 4; r++)
                    C[off + (lg * 4 + r) * 8] = f2bf(acc[i][j][r] * scale);
            }
        }
    } else if constexpr (MODE == 1) {
        uint16_t* C = (uint16_t*)Cg;
#pragma unroll
        for (int i = 0; i < 8; i++) {
            const int gm = m0 + wr * 128 + i * 16 + lg * 4;  // global m = b*SEQ + s
            const int bb = gm / SEQ;                         // uniform per block
            const int s0 = gm - bb * SEQ;                    // s0&7 in {0,4}
            uint16_t* Cb = C + (size_t)bb * DMODEL * SEQ;
#pragma unroll
            for (int j = 0; j < 4; j++) {
                const int e = n0 + wc * 64 + j * 16 + lr;
                const size_t off = ((size_t)(e >> 4) * (SEQ / 8) + (s0 >> 3)) * 128 +
                                   (e & 15) * 8 + (s0 & 7);
                u32x2 v = {pk2(acc[i][j][0], acc[i][j][1]), pk2(acc[i][j][2], acc[i][j][3])};
                *(u32x2*)&Cb[off] = v;
            }
        }
    } else if constexpr (MODE == 2) {
        float* C = (float*)Cg + (size_t)bz * sC;
        const float* LB = Linv + bz * SEQ;
#pragma unroll
        for (int i = 0; i < 8; i++) {
            const int gm = m0 + wr * 128 + i * 16 + lg * 4;
            const f32x4 lv = *(const f32x4*)&LB[gm];
#pragma unroll
            for (int j = 0; j < 4; j++) {
                const int gn = n0 + wc * 64 + j * 16 + lr;
#pragma unroll
                for (int r = 0; r < 4; r++)
                    C[(size_t)(gm + r) * ldc + gn] = acc[i][j][r] * lv[r];
            }
        }
    } else {  // MODE 3: merged projection epilogue
        if (bz < 2) {
            uint16_t* C = (uint16_t*)(bz == 0 ? Cg : C2);
            const float sc = bz == 0 ? scale : 1.0f;
#pragma unroll
            for (int i = 0; i < 8; i++) {
                const int gm = m0 + wr * 128 + i * 16 + lg * 4;
                const size_t pbase = (size_t)(gm >> 4) * (ldc / 8);
#pragma unroll
                for (int j = 0; j < 4; j++) {
                    const int gn = n0 + wc * 64 + j * 16 + lr;
                    const size_t off = (pbase + (gn >> 3)) * 128 + (gn & 7);
#pragma unroll
                    for (int r = 0; r < 4; r++)
                        C[off + (lg * 4 + r) * 8] = f2bf(acc[i][j][r] * sc);
                }
            }
        } else {
            uint16_t* C = (uint16_t*)C3;
#pragma unroll
            for (int i = 0; i < 8; i++) {
                const int gm = m0 + wr * 128 + i * 16 + lg * 4;
                const int bb = gm / SEQ;
                const int s0 = gm - bb * SEQ;
                uint16_t* Cb = C + (size_t)bb * DMODEL * SEQ;
#pragma unroll
                for (int j = 0; j < 4; j++) {
                    const int e = n0 + wc * 64 + j * 16 + lr;
                    const size_t off = ((size_t)(e >> 4) * (SEQ / 8) + (s0 >> 3)) * 128 +
                                       (e & 15) * 8 + (s0 & 7);
                    u32x2 v = {pk2(acc[i][j][0], acc[i][j][1]),
                               pk2(acc[i][j][2], acc[i][j][3])};
                    *(u32x2*)&Cb[off] = v;
                }
            }
        }
    }
}

// ---------------------------------------------------------------------------
// Kernel 3: row softmax on PK-layout S, in place.  One block per 16-row panel
// (contiguous 32KB).  Thread t owns row t&15, k-slots (t>>4)+16u, u=0..15.
// ---------------------------------------------------------------------------
__global__ __launch_bounds__(256) void softmax_pk(uint16_t* __restrict__ S,
                                                  float* __restrict__ Linv) {
    const size_t panel = blockIdx.x;
    uint16_t* sp = S + panel * (size_t)(16 * SEQ);
    const int t = threadIdx.x, lane = t & 63, w = t >> 6;
    const int r15 = t & 15, ksl = t >> 4;
    __shared__ float rm[4][16], rs[4][16];
    u32x4 raw[16];
    float mx = -3.0e38f;
#pragma unroll
    for (int u = 0; u < 16; u++) {
        raw[u] = *(const u32x4*)&sp[(ksl + u * 16) * 128 + r15 * 8];
#pragma unroll
        for (int j = 0; j < 4; j++) {
            mx = fmaxf(mx, __builtin_bit_cast(float, raw[u][j] << 16));
            mx = fmaxf(mx, __builtin_bit_cast(float, raw[u][j] & 0xffff0000u));
        }
    }
    mx = fmaxf(mx, __shfl_xor(mx, 16));
    mx = fmaxf(mx, __shfl_xor(mx, 32));
    if (lane < 16) rm[w][lane] = mx;
    __syncthreads();
    const float m = fmaxf(fmaxf(rm[0][r15], rm[1][r15]), fmaxf(rm[2][r15], rm[3][r15]));
    float sum = 0.0f;
#pragma unroll
    for (int u = 0; u < 16; u++) {
#pragma unroll
        for (int j = 0; j < 4; j++) {
            float lo = __expf(__builtin_bit_cast(float, raw[u][j] << 16) - m);
            float hi = __expf(__builtin_bit_cast(float, raw[u][j] & 0xffff0000u) - m);
            sum += lo + hi;
            raw[u][j] = pk2(lo, hi);
        }
    }
    sum += __shfl_xor(sum, 16);
    sum += __shfl_xor(sum, 32);
    if (lane < 16) rs[w][lane] = sum;
    __syncthreads();
    const float tot = rs[0][r15] + rs[1][r15] + rs[2][r15] + rs[3][r15];
#pragma unroll
    for (int u = 0; u < 16; u++)
        *(u32x4*)&sp[(ksl + u * 16) * 128 + r15 * 8] = raw[u];
    if (w == 0 && lane < 16) Linv[panel * 16 + lane] = 1.0f / tot;
}

// ---------------------------------------------------------------------------
// Buffer plan (aliasing-audited):
//   ws:  Qbf [0, 33.5M)  Kbf [33.5M, 67.1M)  VTb [67.1M, 100.7M)
//        WT  [100.7M, 106.95M)  Linv [106.95M, ~107M)
//        S/P [107,020,288 .. 174,129,152)
//   X casts (all DISJOINT, dead before their region is re-written):
//        XqB = d_out[0 .. 32M)            (PV writes all of d_out at the end)
//        XkB = S + 0       [107,020,288)  (scores writes S after proj done)
//        XvB = S + 33.5MB  [140,574,720)
//   Temporal chain: cast3 -> proj(reads X*, writes Q/K/VT) -> scores(clobbers
//   XkB/XvB) -> softmax -> PV(clobbers XqB, writes full out).
// ---------------------------------------------------------------------------
extern "C" void kernel_launch(void* const* d_in, const int* in_sizes, int n_in,
                              void* d_out, int out_size, void* d_ws, size_t ws_size,
                              hipStream_t stream) {
    const float* Xk = (const float*)d_in[0];
    const float* Xv = (const float*)d_in[1];
    const float* Xq = (const float*)d_in[2];
    const float* Wk = (const float*)d_in[3];
    const float* Wv = (const float*)d_in[4];
    const float* Wq = (const float*)d_in[5];
    float* out = (float*)d_out;
    char* ws = (char*)d_ws;
    uint16_t* Qbf = (uint16_t*)(ws);
    uint16_t* Kbf = (uint16_t*)(ws + (size_t)33554432);
    uint16_t* VTb = (uint16_t*)(ws + (size_t)67108864);
    uint16_t* WT  = (uint16_t*)(ws + (size_t)100663296);
    float*    Linv= (float*)(ws + (size_t)106954752);
    uint16_t* Sb  = (uint16_t*)(ws + (size_t)107020288);
    uint16_t* XqB = (uint16_t*)d_out;                        // 32 MB of 64 MB out
    uint16_t* XkB = Sb;                                      // S + 0
    uint16_t* XvB = (uint16_t*)(ws + (size_t)140574720);     // S + 32 MB

    wt_cast_kernel<<<dim3(32, 32, 3), dim3(32, 8), 0, stream>>>(Wk, Wv, Wq, WT);
    // all three input casts in one dispatch (disjoint destinations)
    cast3_bf16_pk<<<dim3(8192, 3), 256, 0, stream>>>(Xq, Xk, Xv, XqB, XkB, XvB);
    // merged Q/K/V projection: z=0 Q (scale 1/32), z=1 K, z=2 V (VT store)
    gemm8p<3, 0><<<dim3(64, 4, 3), 512, 0, stream>>>(
        XqB, WT, (void*)Qbf, nullptr, 0.03125f,
        DMODEL, DMODEL, DMODEL, DMODEL / 64,
        0, (size_t)1048576 /*WT stride*/, 0,
        XkB, XvB, (void*)Kbf, (void*)VTb);
    // scores: S[b][q][k] = Qhat[b] . K[b]^T  (bf16 PK store), XCD = batch
    gemm8p<0, 1><<<dim3(8, 8, 8), 512, 0, stream>>>(
        Qbf, Kbf, (void*)Sb, nullptr, 1.0f,
        DMODEL, DMODEL, SEQ, DMODEL / 64,
        (size_t)SEQ * DMODEL, (size_t)SEQ * DMODEL, (size_t)SEQ * SEQ,
        nullptr, nullptr, nullptr, nullptr);
    // in-place row softmax -> P, Linv
    softmax_pk<<<dim3(BATCH * SEQ / 16), 256, 0, stream>>>(Sb, Linv);
    // Z[b][q][e] = (P[b] . V[b]) * Linv  (f32 plain store)
    gemm8p<2, 1><<<dim3(8, 8, 4), 512, 0, stream>>>(
        Sb, VTb, (void*)out, Linv, 1.0f,
        SEQ, SEQ, DMODEL, SEQ / 64,
        (size_t)SEQ * SEQ, (size_t)DMODEL * SEQ, (size_t)SEQ * DMODEL,
        nullptr, nullptr, nullptr, nullptr);
}